// Round 5
// baseline (138.223 us; speedup 1.0000x reference)
//
#include <hip/hip_runtime.h>
#include <math.h>

#define NB 16          // images
#define NP 100         // predictions per image
#define NT 320         // total targets
#define NCLS 80        // classes
#define WO 128         // output mask width/height
#define HW 16384       // 128*128
#define QT 1600        // NB*NP
#define PI 20          // targets per image
#define KSPLIT 8
#define KSLICE 2048    // HW/KSPLIT  (same slice boundaries as round 3 -> bit-identical num)
#define BK 32
#define KTILES 64      // KSLICE/BK
#define SRC_W 256
#define BM 32
#define BN 320
#define CH 16          // output rows per downsample block

typedef _Float16 half2v __attribute__((ext_vector_type(2)));
typedef _Float16 half4v __attribute__((ext_vector_type(4)));
typedef _Float16 half8v __attribute__((ext_vector_type(8)));
typedef float f32x4 __attribute__((ext_vector_type(4)));

#define GLOAD_LDS16(gp, lp) __builtin_amdgcn_global_load_lds(                         \
    (const __attribute__((address_space(1))) void*)(gp),                              \
    (__attribute__((address_space(3))) void*)(lp), 16, 0, 0)

// LDS swizzle for 64B-row-stride tiles: 16B-slot ^= (r&3)^((r>>2)&3)  -> uniform 2-way (free)
#define SWZ(r) (((r) & 3) ^ (((r) >> 2) & 3))

__device__ __forceinline__ float sigf(float x){ return 1.0f/(1.0f+expf(-x)); }
__device__ __forceinline__ float sigfast(float x){ return 1.0f/(1.0f+__expf(-x)); }

// jax.image.resize(linear, antialias=True) 2x-downsample weights, 256 -> 128
__device__ __forceinline__ void mkw128(int i, float* w, int* ix){
  int j0 = 2*i - 1;
  ix[0]=j0; ix[1]=j0+1; ix[2]=j0+2; ix[3]=j0+3;
  w[0]=0.125f; w[1]=0.375f; w[2]=0.375f; w[3]=0.125f;
  if (i == 0){ ix[0]=0; w[0]=0.0f; w[1]=3.0f/7.0f; w[2]=3.0f/7.0f; w[3]=1.0f/7.0f; }
  if (i == 127){ ix[3]=255; w[3]=0.0f; w[0]=1.0f/7.0f; w[1]=3.0f/7.0f; w[2]=3.0f/7.0f; }
}

// K1: separable downsample, one block per (target, 16-row output chunk).
__global__ __launch_bounds__(256) void k_downsample(const float* __restrict__ tgt,
                                                    _Float16* __restrict__ tm,
                                                    float* __restrict__ tqpart){
  const int blk = blockIdx.x;
  const int t = blk >> 3;
  const int c = blk & 7;               // chunk: output rows [c*16, c*16+16)
  const int x = threadIdx.x;           // input column 0..255
  const int oy0 = c * CH;
  const int r0 = 2*oy0 - 1;            // first needed input row (may be -1)
  const float* src = tgt + (size_t)t * (SRC_W*SRC_W);
  __shared__ float vbuf[CH][SRC_W];
  __shared__ float wred[4];

  float cc[34];
  #pragma unroll
  for (int li = 0; li < 34; ++li){
    int r = r0 + li; r = r < 0 ? 0 : (r > 255 ? 255 : r);
    cc[li] = src[r*SRC_W + x];
  }
  #pragma unroll
  for (int dy = 0; dy < CH; ++dy){
    int oy = oy0 + dy;
    float w0=0.125f, w1=0.375f, w2=0.375f, w3=0.125f;
    if (oy == 0){ w0=0.0f; w1=3.0f/7.0f; w2=3.0f/7.0f; w3=1.0f/7.0f; }
    if (oy == 127){ w3=0.0f; w0=1.0f/7.0f; w1=3.0f/7.0f; w2=3.0f/7.0f; }
    vbuf[dy][x] = w0*cc[2*dy] + w1*cc[2*dy+1] + w2*cc[2*dy+2] + w3*cc[2*dy+3];
  }
  __syncthreads();

  float ssq = 0.f;
  _Float16* dst = tm + (size_t)t * HW + (size_t)oy0 * WO;
  #pragma unroll
  for (int i = 0; i < 8; ++i){
    int e = x + 256*i;                 // 0..2047
    int oy = e >> 7;                   // local output row 0..15
    int ox = e & 127;
    float w[4]; int ix[4];
    mkw128(ox, w, ix);
    float val = w[0]*vbuf[oy][ix[0]] + w[1]*vbuf[oy][ix[1]]
              + w[2]*vbuf[oy][ix[2]] + w[3]*vbuf[oy][ix[3]];
    dst[oy*WO + ox] = (_Float16)val;
    ssq += val*val;
  }
  for (int off=32; off; off>>=1) ssq += __shfl_xor(ssq, off);
  if ((x & 63) == 0) wred[x >> 6] = ssq;
  __syncthreads();
  if (x == 0) tqpart[c*NT + t] = wred[0]+wred[1]+wred[2]+wred[3];
}

// K3: MFMA fp16 GEMM  part[z][q][t] = sum_{k in slice z} sigmoid(A[q][k]) * Tm[t][k]
// BM=32 x BN=320 x BK=32, KSPLIT=8, 512 threads (8 waves, each 16x80).
// Grid 400 blocks, z = id&7 XCD-pins each K-slab's B to one L2.
// fp32 partials, K-chunk-of-32 ascending accumulation: num bit-identical to round 3.
__global__ __launch_bounds__(512) void k_gemm(const float* __restrict__ A,
                                              const _Float16* __restrict__ Bm,
                                              float* __restrict__ part,
                                              float* __restrict__ pqpart){
  __shared__ _Float16 As[2][BM*BK];    // 2 x 2 KB
  __shared__ _Float16 Bs[2][BN*BK];    // 2 x 20 KB
  const int tid = threadIdx.x;
  const int lane = tid & 63;
  const int wid = tid >> 6;            // 0..7
  const int wr = wid & 1;              // row group: wr*16
  const int wc = wid >> 1;             // col group: wc*80
  const int id = blockIdx.x;
  const int z = id & 7;                // id%8 -> XCD-pinned K-slab
  const int q0 = (id >> 3) * BM;
  const int ks = z * KSLICE;

  // A-staging: row = tid>>4 (0..31), float2 at col (tid&15)*2
  const int ar = tid >> 4;
  const int acg = tid & 15;
  const float* ap = A + (size_t)(q0 + ar) * HW + ks + acg*2;
  const int awoff = ar*BK + ((acg >> 2) ^ SWZ(ar))*8 + (acg & 3)*2;

  f32x4 acc[5];
  #pragma unroll
  for (int n = 0; n < 5; ++n) acc[n] = (f32x4){0.f,0.f,0.f,0.f};
  float pqs = 0.f;

  // prologue: stage tile 0
  #pragma unroll
  for (int i = 0; i < 3; ++i){
    int g = i*512 + tid;               // 16B chunk 0..1279
    if (g < 1280){
      int row = g >> 2, slot = g & 3;
      const _Float16* gp = Bm + (size_t)row*HW + ks + (slot ^ SWZ(row))*8;
      GLOAD_LDS16(gp, &Bs[0][(size_t)g*8]);
    }
  }
  {
    float2 a0 = *(const float2*)ap;
    float s0 = sigfast(a0.x), s1 = sigfast(a0.y);
    pqs += s0*s0 + s1*s1;
    half2v hh = { (_Float16)s0, (_Float16)s1 };
    *(half2v*)&As[0][awoff] = hh;
  }
  __syncthreads();

  for (int kt = 0; kt < KTILES; ++kt){
    const int cur = kt & 1, nxt = cur ^ 1;
    float2 a;
    if (kt + 1 < KTILES){
      #pragma unroll
      for (int i = 0; i < 3; ++i){
        int g = i*512 + tid;
        if (g < 1280){
          int row = g >> 2, slot = g & 3;
          const _Float16* gp = Bm + (size_t)row*HW + ks + (kt+1)*BK + (slot ^ SWZ(row))*8;
          GLOAD_LDS16(gp, &Bs[nxt][(size_t)g*8]);
        }
      }
      a = *(const float2*)(ap + (kt+1)*BK);
    }
    // MFMA on cur
    half8v af, bf[5];
    {
      int r = wr*16 + (lane & 15);
      af = *(const half8v*)&As[cur][r*BK + (((lane>>4) ^ SWZ(r)))*8];
    }
    #pragma unroll
    for (int n = 0; n < 5; ++n){
      int r = wc*80 + n*16 + (lane & 15);
      bf[n] = *(const half8v*)&Bs[cur][r*BK + (((lane>>4) ^ SWZ(r)))*8];
    }
    #pragma unroll
    for (int n = 0; n < 5; ++n)
      acc[n] = __builtin_amdgcn_mfma_f32_16x16x32_f16(af, bf[n], acc[n], 0, 0, 0);
    // sigmoid for next tile -> As[nxt] (A-load latency hidden under MFMAs)
    if (kt + 1 < KTILES){
      float s0 = sigfast(a.x), s1 = sigfast(a.y);
      pqs += s0*s0 + s1*s1;
      half2v hh = { (_Float16)s0, (_Float16)s1 };
      *(half2v*)&As[nxt][awoff] = hh;
    }
    __syncthreads();
  }

  // write split-K partials (fp32): C/D layout col=lane&15, row=(lane>>4)*4+reg
  float* op = part + (size_t)z * (QT*NT);
  {
    int qb = q0 + wr*16 + (lane >> 4)*4;
    #pragma unroll
    for (int n = 0; n < 5; ++n){
      int t = wc*80 + n*16 + (lane & 15);
      #pragma unroll
      for (int r = 0; r < 4; ++r)
        op[(size_t)(qb + r)*NT + t] = acc[n][r];
    }
  }
  // pq partial: 16 threads per row
  pqs += __shfl_xor(pqs, 1);
  pqs += __shfl_xor(pqs, 2);
  pqs += __shfl_xor(pqs, 4);
  pqs += __shfl_xor(pqs, 8);
  if ((tid & 15) == 0) pqpart[z*QT + q0 + ar] = pqs;
}

// K4: final cost C = dice^0.8 * prob^0.2 (reduces split-K partials of num, pq, tq)
__global__ __launch_bounds__(256) void k_cost(const float* __restrict__ part,
                                              const float* __restrict__ pqpart,
                                              const float* __restrict__ tqpart,
                                              const float* __restrict__ logits,
                                              const int* __restrict__ ids,
                                              float* __restrict__ Cout){
  int idx = blockIdx.x * 256 + threadIdx.x;
  int q = idx / NT;
  int t = idx - q * NT;
  float num = 0.f;
  #pragma unroll
  for (int s = 0; s < KSPLIT; ++s) num += part[(size_t)s * (QT*NT) + idx];
  num *= 2.0f;
  float pqv = 0.f;
  #pragma unroll
  for (int s = 0; s < KSPLIT; ++s) pqv += pqpart[s * QT + q];
  float tqv = 0.f;
  #pragma unroll
  for (int s = 0; s < 8; ++s) tqv += tqpart[s * NT + t];
  float den = pqv + tqv + 1e-4f;
  float dice = num / den;
  float prob = sigf(logits[q * NCLS + ids[t]]);
  Cout[idx] = powf(dice, 0.8f) * powf(prob, 0.2f);
}

// K5: Hungarian (JV / e-maxx with potentials), transposed: 20 rows (targets) x 100 cols (preds).
__global__ __launch_bounds__(64) void k_hung(const float* __restrict__ C,
                                             float* __restrict__ rows_out,
                                             float* __restrict__ cols_out){
  const int b = blockIdx.x;
  const int lane = threadIdx.x;
  __shared__ float negC[PI*NP];     // [i][j] = -C[b, j, b*PI + i]
  __shared__ double u[PI+1];
  __shared__ int p[NP+1];
  __shared__ int way[NP+1];
  for (int e = lane; e < PI*NP; e += 64){
    int i = e / NP, j = e - i*NP;
    negC[e] = -C[(size_t)(b*NP + j)*NT + (b*PI + i)];
  }
  if (lane <= PI) u[lane] = 0.0;
  for (int j = lane; j <= NP; j += 64){ p[j] = 0; way[j] = 0; }
  __syncthreads();
  const int jA = lane + 1;           // 1..64
  const int jB = lane + 65;          // 65..128
  const bool hasB = (jB <= NP);
  double vA = 0.0, vB = 0.0;
  const double INFD = 1e18;
  for (int i = 1; i <= PI; ++i){
    if (lane == 0) p[0] = i;
    __syncthreads();
    double mvA = INFD, mvB = INFD;
    bool usA = false, usB = false;
    int j0 = 0;
    int jbrk = 0;
    while (true){
      if (jA == j0) usA = true;
      if (hasB && jB == j0) usB = true;
      int i0 = p[j0];
      double ui0 = u[i0];
      double candA = INFD, candB = INFD;
      if (!usA){
        double cur = (double)negC[(i0-1)*NP + (jA-1)] - ui0 - vA;
        if (cur < mvA){ mvA = cur; way[jA] = j0; }
        candA = mvA;
      }
      if (hasB && !usB){
        double cur = (double)negC[(i0-1)*NP + (jB-1)] - ui0 - vB;
        if (cur < mvB){ mvB = cur; way[jB] = j0; }
        candB = mvB;
      }
      double bv; int bj;
      if (candB < candA){ bv = candB; bj = jB; } else { bv = candA; bj = jA; }
      for (int off = 32; off; off >>= 1){
        double ov = __shfl_xor(bv, off);
        int oj = __shfl_xor(bj, off);
        if (ov < bv || (ov == bv && oj < bj)){ bv = ov; bj = oj; }
      }
      const double delta = bv;
      if (usA){ int pj = p[jA]; u[pj] += delta; vA -= delta; }
      else mvA -= delta;
      if (hasB){
        if (usB){ int pj = p[jB]; u[pj] += delta; vB -= delta; }
        else mvB -= delta;
      }
      if (lane == 0) u[p[0]] += delta;   // virtual column 0 carries the new row
      __syncthreads();
      j0 = bj;
      if (p[j0] == 0){ jbrk = j0; break; }
    }
    __syncthreads();
    if (lane == 0){
      int j0a = jbrk;
      while (j0a){
        int jp = way[j0a];
        p[j0a] = p[jp];
        j0a = jp;
      }
    }
    __syncthreads();
  }
  if (lane == 0){
    int cnt = 0;
    for (int j = 1; j <= NP; ++j){
      int pi = p[j];
      if (pi != 0){
        rows_out[b*PI + cnt] = (float)(j - 1);   // prediction index, ascending
        cols_out[b*PI + cnt] = (float)(pi - 1);  // target index within image
        ++cnt;
      }
    }
  }
}

extern "C" void kernel_launch(void* const* d_in, const int* in_sizes, int n_in,
                              void* d_out, int out_size, void* d_ws, size_t ws_size,
                              hipStream_t stream){
  const float* pred_masks  = (const float*)d_in[0];
  const float* pred_logits = (const float*)d_in[1];
  const float* tgt_masks   = (const float*)d_in[2];
  const int*   tgt_ids     = (const int*)d_in[3];
  float* out = (float*)d_out;
  char* ws = (char*)d_ws;
  _Float16* Th  = (_Float16*)ws;                                    // 10.49 MB
  float* tqpart = (float*)(ws + (size_t)NT*HW*2);                   // 8*320 f32
  float* pqpart = (float*)(ws + (size_t)NT*HW*2 + 16384);           // 8*1600 f32
  float* part   = (float*)(ws + (size_t)NT*HW*2 + 16384 + 65536);   // 8*512000 f32 = 16.4 MB

  k_downsample<<<NT*8, 256, 0, stream>>>(tgt_masks, Th, tqpart);
  k_gemm<<<50*KSPLIT, 512, 0, stream>>>(pred_masks, Th, part, pqpart);
  k_cost<<<(QT*NT)/256, 256, 0, stream>>>(part, pqpart, tqpart, pred_logits, tgt_ids, out);
  k_hung<<<NB, 64, 0, stream>>>(out, out + (size_t)QT*NT, out + (size_t)QT*NT + NT);
}

// Round 6
// 132.534 us; speedup vs baseline: 1.0429x; 1.0429x over previous
//
#include <hip/hip_runtime.h>
#include <math.h>

#define NB 16          // images
#define NP 100         // predictions per image
#define NT 320         // total targets
#define NCLS 80        // classes
#define WO 128         // output mask width/height
#define HW 16384       // 128*128
#define QT 1600        // NB*NP
#define PI 20          // targets per image
#define KSPLIT 8
#define KSLICE 2048    // HW/KSPLIT  (same slice boundaries as r3/r5 -> bit-identical num)
#define BK 32
#define KTILES 64      // KSLICE/BK
#define SRC_W 256
#define BM 32
#define BN 320
#define CH 16          // output rows per downsample block

typedef _Float16 half4v __attribute__((ext_vector_type(4)));
typedef _Float16 half8v __attribute__((ext_vector_type(8)));
typedef float f32x4 __attribute__((ext_vector_type(4)));

#define GLOAD_LDS16(gp, lp) __builtin_amdgcn_global_load_lds(                         \
    (const __attribute__((address_space(1))) void*)(gp),                              \
    (__attribute__((address_space(3))) void*)(lp), 16, 0, 0)

// LDS swizzle for 64B-row-stride tiles: 16B-slot ^= (r&3)^((r>>2)&3)
#define SWZ(r) (((r) & 3) ^ (((r) >> 2) & 3))

__device__ __forceinline__ float sigf(float x){ return 1.0f/(1.0f+expf(-x)); }
__device__ __forceinline__ float sigfast(float x){ return 1.0f/(1.0f+__expf(-x)); }

// jax.image.resize(linear, antialias=True) 2x-downsample weights, 256 -> 128
__device__ __forceinline__ void mkw128(int i, float* w, int* ix){
  int j0 = 2*i - 1;
  ix[0]=j0; ix[1]=j0+1; ix[2]=j0+2; ix[3]=j0+3;
  w[0]=0.125f; w[1]=0.375f; w[2]=0.375f; w[3]=0.125f;
  if (i == 0){ ix[0]=0; w[0]=0.0f; w[1]=3.0f/7.0f; w[2]=3.0f/7.0f; w[3]=1.0f/7.0f; }
  if (i == 127){ ix[3]=255; w[3]=0.0f; w[0]=1.0f/7.0f; w[1]=3.0f/7.0f; w[2]=3.0f/7.0f; }
}

// K1: separable downsample, one block per (target, 16-row output chunk).
__global__ __launch_bounds__(256) void k_downsample(const float* __restrict__ tgt,
                                                    _Float16* __restrict__ tm,
                                                    float* __restrict__ tqpart){
  const int blk = blockIdx.x;
  const int t = blk >> 3;
  const int c = blk & 7;               // chunk: output rows [c*16, c*16+16)
  const int x = threadIdx.x;           // input column 0..255
  const int oy0 = c * CH;
  const int r0 = 2*oy0 - 1;            // first needed input row (may be -1)
  const float* src = tgt + (size_t)t * (SRC_W*SRC_W);
  __shared__ float vbuf[CH][SRC_W];
  __shared__ float wred[4];

  float cc[34];
  #pragma unroll
  for (int li = 0; li < 34; ++li){
    int r = r0 + li; r = r < 0 ? 0 : (r > 255 ? 255 : r);
    cc[li] = src[r*SRC_W + x];
  }
  #pragma unroll
  for (int dy = 0; dy < CH; ++dy){
    int oy = oy0 + dy;
    float w0=0.125f, w1=0.375f, w2=0.375f, w3=0.125f;
    if (oy == 0){ w0=0.0f; w1=3.0f/7.0f; w2=3.0f/7.0f; w3=1.0f/7.0f; }
    if (oy == 127){ w3=0.0f; w0=1.0f/7.0f; w1=3.0f/7.0f; w2=3.0f/7.0f; }
    vbuf[dy][x] = w0*cc[2*dy] + w1*cc[2*dy+1] + w2*cc[2*dy+2] + w3*cc[2*dy+3];
  }
  __syncthreads();

  float ssq = 0.f;
  _Float16* dst = tm + (size_t)t * HW + (size_t)oy0 * WO;
  #pragma unroll
  for (int i = 0; i < 8; ++i){
    int e = x + 256*i;                 // 0..2047
    int oy = e >> 7;                   // local output row 0..15
    int ox = e & 127;
    float w[4]; int ix[4];
    mkw128(ox, w, ix);
    float val = w[0]*vbuf[oy][ix[0]] + w[1]*vbuf[oy][ix[1]]
              + w[2]*vbuf[oy][ix[2]] + w[3]*vbuf[oy][ix[3]];
    dst[oy*WO + ox] = (_Float16)val;
    ssq += val*val;
  }
  for (int off=32; off; off>>=1) ssq += __shfl_xor(ssq, off);
  if ((x & 63) == 0) wred[x >> 6] = ssq;
  __syncthreads();
  if (x == 0) tqpart[c*NT + t] = wred[0]+wred[1]+wred[2]+wred[3];
}

// K3: MFMA fp16 GEMM  part[z][q][t] = sum_{k in slice z} sigmoid(A[q][k]) * Tm[t][k]
// BM=32 x BN=320 x BK=32, KSPLIT=8, 256 threads (4 waves, each 32x80, 10 MFMA/step).
// Triple-buffered B via global_load_lds + counted s_waitcnt vmcnt(6) (never 0 in loop),
// raw s_barrier; A 2-deep register pipeline + double-buffered As.
// MFMA chain identical to r5 -> num bit-identical.
__global__ __launch_bounds__(256) void k_gemm(const float* __restrict__ A,
                                              const _Float16* __restrict__ Bm,
                                              float* __restrict__ part,
                                              float* __restrict__ pqpart){
  __shared__ _Float16 Bs[3][BN*BK];    // 3 x 20 KB
  __shared__ _Float16 As[2][BM*BK];    // 2 x 2 KB
  const int tid = threadIdx.x;
  const int lane = tid & 63;
  const int wid = tid >> 6;            // 0..3 -> 80-col group
  const int id = blockIdx.x;
  const int z = id & 7;                // id%8 -> XCD-pinned K-slab
  const int q0 = (id >> 3) * BM;
  const int ks = z * KSLICE;

  // A-staging: row = tid>>3 (0..31), float4 at col (tid&7)*4
  const int ar = tid >> 3;
  const int acg = tid & 7;
  const float* ap = A + (size_t)(q0 + ar) * HW + ks + acg*4;
  const int awoff = ar*BK + ((acg >> 1) ^ SWZ(ar))*8 + (acg & 1)*4;

  f32x4 acc[2][5];
  #pragma unroll
  for (int i = 0; i < 2; ++i)
    #pragma unroll
    for (int n = 0; n < 5; ++n) acc[i][n] = (f32x4){0.f,0.f,0.f,0.f};
  float pqs = 0.f;

  // ---- prologue ----
  {  // A(0) -> As[0]  (full drain here is fine, once)
    float4 a0 = *(const float4*)ap;
    float s0 = sigfast(a0.x), s1 = sigfast(a0.y), s2 = sigfast(a0.z), s3 = sigfast(a0.w);
    pqs += s0*s0 + s1*s1 + s2*s2 + s3*s3;
    half4v hh = { (_Float16)s0, (_Float16)s1, (_Float16)s2, (_Float16)s3 };
    *(half4v*)&As[0][awoff] = hh;
  }
  #pragma unroll
  for (int i = 0; i < 5; ++i){         // B(0) -> Bs[0]
    int g = i*256 + tid;               // 16B chunk 0..1279
    int row = g >> 2, slot = g & 3;
    GLOAD_LDS16(Bm + (size_t)row*HW + ks + (slot ^ SWZ(row))*8, &Bs[0][(size_t)g*8]);
  }
  #pragma unroll
  for (int i = 0; i < 5; ++i){         // B(1) -> Bs[1]
    int g = i*256 + tid;
    int row = g >> 2, slot = g & 3;
    GLOAD_LDS16(Bm + (size_t)row*HW + ks + BK + (slot ^ SWZ(row))*8, &Bs[1][(size_t)g*8]);
  }
  float4 aCur = *(const float4*)(ap + BK);   // A(1) in flight
  asm volatile("s_waitcnt vmcnt(5) lgkmcnt(0)" ::: "memory");  // B(0)+As(0) ready
  __builtin_amdgcn_s_barrier();

  // ---- main loop: one raw barrier per K-step, vmcnt never drained ----
  for (int kt = 0; kt < KTILES; ++kt){
    float4 aNext;
    if (kt + 2 < KTILES){
      aNext = *(const float4*)(ap + (kt+2)*BK);     // issue A(kt+2) FIRST (stays oldest)
      const _Float16* bbase = Bm + (size_t)(ks + (kt+2)*BK);
      _Float16* lds = &Bs[(kt+2)%3][0];
      #pragma unroll
      for (int i = 0; i < 5; ++i){
        int g = i*256 + tid;
        int row = g >> 2, slot = g & 3;
        GLOAD_LDS16(bbase + (size_t)row*HW + (slot ^ SWZ(row))*8, lds + (size_t)g*8);
      }
    }
    // compute tile kt
    const _Float16* bb = &Bs[kt%3][0];
    const _Float16* aa = &As[kt&1][0];
    half8v af[2], bf[5];
    #pragma unroll
    for (int i = 0; i < 2; ++i){
      int r = i*16 + (lane & 15);
      af[i] = *(const half8v*)&aa[r*BK + (((lane>>4) ^ SWZ(r)))*8];
    }
    #pragma unroll
    for (int n = 0; n < 5; ++n){
      int r = wid*80 + n*16 + (lane & 15);
      bf[n] = *(const half8v*)&bb[r*BK + (((lane>>4) ^ SWZ(r)))*8];
    }
    #pragma unroll
    for (int i = 0; i < 2; ++i)
      #pragma unroll
      for (int n = 0; n < 5; ++n)
        acc[i][n] = __builtin_amdgcn_mfma_f32_16x16x32_f16(af[i], bf[n], acc[i][n], 0, 0, 0);
    // sigmoid A(kt+1) -> As[(kt+1)&1] (aCur loaded one iteration ago)
    if (kt + 1 < KTILES){
      float s0 = sigfast(aCur.x), s1 = sigfast(aCur.y), s2 = sigfast(aCur.z), s3 = sigfast(aCur.w);
      pqs += s0*s0 + s1*s1 + s2*s2 + s3*s3;
      half4v hh = { (_Float16)s0, (_Float16)s1, (_Float16)s2, (_Float16)s3 };
      *(half4v*)&As[(kt+1)&1][awoff] = hh;
      aCur = aNext;
    }
    if (kt + 2 < KTILES){
      asm volatile("s_waitcnt vmcnt(6) lgkmcnt(0)" ::: "memory");  // leave aNext+B(kt+2); B(kt+1) landed
    } else {
      asm volatile("s_waitcnt vmcnt(0) lgkmcnt(0)" ::: "memory");  // tail drain
    }
    __builtin_amdgcn_s_barrier();
  }

  // write split-K partials (fp32): C/D layout col=lane&15, row=(lane>>4)*4+reg
  float* op = part + (size_t)z * (QT*NT);
  #pragma unroll
  for (int i = 0; i < 2; ++i){
    int qb = q0 + i*16 + (lane >> 4)*4;
    #pragma unroll
    for (int n = 0; n < 5; ++n){
      int t = wid*80 + n*16 + (lane & 15);
      #pragma unroll
      for (int r = 0; r < 4; ++r)
        op[(size_t)(qb + r)*NT + t] = acc[i][n][r];
    }
  }
  // pq partial: 8 threads per row (tid&7), all within one wave
  pqs += __shfl_xor(pqs, 1);
  pqs += __shfl_xor(pqs, 2);
  pqs += __shfl_xor(pqs, 4);
  if ((tid & 7) == 0) pqpart[z*QT + q0 + ar] = pqs;
}

// K4: final cost C = dice^0.8 * prob^0.2 (reduces split-K partials of num, pq, tq)
__global__ __launch_bounds__(256) void k_cost(const float* __restrict__ part,
                                              const float* __restrict__ pqpart,
                                              const float* __restrict__ tqpart,
                                              const float* __restrict__ logits,
                                              const int* __restrict__ ids,
                                              float* __restrict__ Cout){
  int idx = blockIdx.x * 256 + threadIdx.x;
  int q = idx / NT;
  int t = idx - q * NT;
  float num = 0.f;
  #pragma unroll
  for (int s = 0; s < KSPLIT; ++s) num += part[(size_t)s * (QT*NT) + idx];
  num *= 2.0f;
  float pqv = 0.f;
  #pragma unroll
  for (int s = 0; s < KSPLIT; ++s) pqv += pqpart[s * QT + q];
  float tqv = 0.f;
  #pragma unroll
  for (int s = 0; s < 8; ++s) tqv += tqpart[s * NT + t];
  float den = pqv + tqv + 1e-4f;
  float dice = num / den;
  float prob = sigf(logits[q * NCLS + ids[t]]);
  Cout[idx] = powf(dice, 0.8f) * powf(prob, 0.2f);
}

// K5: Hungarian (JV / e-maxx with potentials), transposed: 20 rows (targets) x 100 cols (preds).
__global__ __launch_bounds__(64) void k_hung(const float* __restrict__ C,
                                             float* __restrict__ rows_out,
                                             float* __restrict__ cols_out){
  const int b = blockIdx.x;
  const int lane = threadIdx.x;
  __shared__ float negC[PI*NP];     // [i][j] = -C[b, j, b*PI + i]
  __shared__ double u[PI+1];
  __shared__ int p[NP+1];
  __shared__ int way[NP+1];
  for (int e = lane; e < PI*NP; e += 64){
    int i = e / NP, j = e - i*NP;
    negC[e] = -C[(size_t)(b*NP + j)*NT + (b*PI + i)];
  }
  if (lane <= PI) u[lane] = 0.0;
  for (int j = lane; j <= NP; j += 64){ p[j] = 0; way[j] = 0; }
  __syncthreads();
  const int jA = lane + 1;           // 1..64
  const int jB = lane + 65;          // 65..128
  const bool hasB = (jB <= NP);
  double vA = 0.0, vB = 0.0;
  const double INFD = 1e18;
  for (int i = 1; i <= PI; ++i){
    if (lane == 0) p[0] = i;
    __syncthreads();
    double mvA = INFD, mvB = INFD;
    bool usA = false, usB = false;
    int j0 = 0;
    int jbrk = 0;
    while (true){
      if (jA == j0) usA = true;
      if (hasB && jB == j0) usB = true;
      int i0 = p[j0];
      double ui0 = u[i0];
      double candA = INFD, candB = INFD;
      if (!usA){
        double cur = (double)negC[(i0-1)*NP + (jA-1)] - ui0 - vA;
        if (cur < mvA){ mvA = cur; way[jA] = j0; }
        candA = mvA;
      }
      if (hasB && !usB){
        double cur = (double)negC[(i0-1)*NP + (jB-1)] - ui0 - vB;
        if (cur < mvB){ mvB = cur; way[jB] = j0; }
        candB = mvB;
      }
      double bv; int bj;
      if (candB < candA){ bv = candB; bj = jB; } else { bv = candA; bj = jA; }
      for (int off = 32; off; off >>= 1){
        double ov = __shfl_xor(bv, off);
        int oj = __shfl_xor(bj, off);
        if (ov < bv || (ov == bv && oj < bj)){ bv = ov; bj = oj; }
      }
      const double delta = bv;
      if (usA){ int pj = p[jA]; u[pj] += delta; vA -= delta; }
      else mvA -= delta;
      if (hasB){
        if (usB){ int pj = p[jB]; u[pj] += delta; vB -= delta; }
        else mvB -= delta;
      }
      if (lane == 0) u[p[0]] += delta;   // virtual column 0 carries the new row
      __syncthreads();
      j0 = bj;
      if (p[j0] == 0){ jbrk = j0; break; }
    }
    __syncthreads();
    if (lane == 0){
      int j0a = jbrk;
      while (j0a){
        int jp = way[j0a];
        p[j0a] = p[jp];
        j0a = jp;
      }
    }
    __syncthreads();
  }
  if (lane == 0){
    int cnt = 0;
    for (int j = 1; j <= NP; ++j){
      int pi = p[j];
      if (pi != 0){
        rows_out[b*PI + cnt] = (float)(j - 1);   // prediction index, ascending
        cols_out[b*PI + cnt] = (float)(pi - 1);  // target index within image
        ++cnt;
      }
    }
  }
}

extern "C" void kernel_launch(void* const* d_in, const int* in_sizes, int n_in,
                              void* d_out, int out_size, void* d_ws, size_t ws_size,
                              hipStream_t stream){
  const float* pred_masks  = (const float*)d_in[0];
  const float* pred_logits = (const float*)d_in[1];
  const float* tgt_masks   = (const float*)d_in[2];
  const int*   tgt_ids     = (const int*)d_in[3];
  float* out = (float*)d_out;
  char* ws = (char*)d_ws;
  _Float16* Th  = (_Float16*)ws;                                    // 10.49 MB
  float* tqpart = (float*)(ws + (size_t)NT*HW*2);                   // 8*320 f32
  float* pqpart = (float*)(ws + (size_t)NT*HW*2 + 16384);           // 8*1600 f32
  float* part   = (float*)(ws + (size_t)NT*HW*2 + 16384 + 65536);   // 8*512000 f32 = 16.4 MB

  k_downsample<<<NT*8, 256, 0, stream>>>(tgt_masks, Th, tqpart);
  k_gemm<<<50*KSPLIT, 256, 0, stream>>>(pred_masks, Th, part, pqpart);
  k_cost<<<(QT*NT)/256, 256, 0, stream>>>(part, pqpart, tqpart, pred_logits, tgt_ids, out);
  k_hung<<<NB, 64, 0, stream>>>(out, out + (size_t)QT*NT, out + (size_t)QT*NT + NT);
}